// Round 17
// baseline (550.965 us; speedup 1.0000x reference)
//
#include <hip/hip_runtime.h>
#include <hip/hip_bf16.h>

typedef _Float16 half8 __attribute__((ext_vector_type(8)));
typedef _Float16 half4 __attribute__((ext_vector_type(4)));
typedef float floatx4 __attribute__((ext_vector_type(4)));

#define EMBED 1024
#define SEQ   2048
#define BATCH 32
#define M_TOT (BATCH * SEQ)   // 65536 rows
#define KDIM  1024
#define NDIM  1024

// async global->LDS, 16B per lane, dest = wave-uniform base + lane*16
#define GLOAD16(g, l) __builtin_amdgcn_global_load_lds(                      \
    (const __attribute__((address_space(1))) void*)(g),                      \
    (__attribute__((address_space(3))) void*)(l), 16, 0, 0)

// ---------------------------------------------------------------------------
// Kernel 1: transpose + convert W[K][N] fp32 -> Wt[N][K] fp16
// ---------------------------------------------------------------------------
__global__ void transpose_w_kernel(const float* __restrict__ W,
                                   _Float16* __restrict__ Wt) {
    __shared__ float t[32][33];
    const int kt = blockIdx.x * 32;
    const int nt = blockIdx.y * 32;
    #pragma unroll
    for (int i = 0; i < 4; ++i)
        t[threadIdx.y + 8 * i][threadIdx.x] =
            W[(size_t)(kt + threadIdx.y + 8 * i) * NDIM + nt + threadIdx.x];
    __syncthreads();
    #pragma unroll
    for (int i = 0; i < 4; ++i)
        Wt[(size_t)(nt + threadIdx.y + 8 * i) * KDIM + kt + threadIdx.x] =
            (_Float16)t[threadIdx.x][threadIdx.y + 8 * i];
}

// ---------------------------------------------------------------------------
// Kernel 2: zero scores + out
// ---------------------------------------------------------------------------
__global__ void zero_kernel(float* __restrict__ scores, float* __restrict__ out) {
    const int i = blockIdx.x * 256 + threadIdx.x;
    if (i < M_TOT) scores[i] = 0.0f;
    if (i < BATCH * EMBED) out[i] = 0.0f;
}

// ---------------------------------------------------------------------------
// Kernel 2b: convert x fp32 -> fp16 (64M elements)
// ---------------------------------------------------------------------------
__global__ __launch_bounds__(256) void cvt_x_kernel(const float* __restrict__ x,
                                                    _Float16* __restrict__ x16) {
    const size_t stride = (size_t)gridDim.x * 256 * 8;
    for (size_t i = ((size_t)blockIdx.x * 256 + threadIdx.x) * 8;
         i < (size_t)M_TOT * KDIM; i += stride) {
        const float4 a = *(const float4*)(x + i);
        const float4 b = *(const float4*)(x + i + 4);
        half8 h;
        h[0] = (_Float16)a.x; h[1] = (_Float16)a.y; h[2] = (_Float16)a.z; h[3] = (_Float16)a.w;
        h[4] = (_Float16)b.x; h[5] = (_Float16)b.y; h[6] = (_Float16)b.z; h[7] = (_Float16)b.w;
        *(half8*)(x16 + i) = h;
    }
}

// ---------------------------------------------------------------------------
// Kernel 3 (ABLATION TEMPLATE, m233-style decomposition of r16's GEMM):
//   V0 = full kernel (real output)
//   V1 = ds_read + MFMA only (no stage, no sync)   -> LDS-read pipe cost
//   V2 = MFMA only (synthetic frags, no mem/sync)  -> MFMA issue floor
//   V3 = stage + vmcnt + barriers only (no compute)-> staging complex cost
// All non-V0 variants write to a scratch buffer; their numerics are
// irrelevant, only their per-dispatch dur_us (rocprof) matters.
// Geometry identical across variants: BM=256, BN=128, BK=32, 512 thr,
// 48 KB LDS, verified conflict-free swizzle, counted vmcnt(3).
// ---------------------------------------------------------------------------
template <int V>
__global__ __launch_bounds__(512, 4) void score_gemm_abl(
    const _Float16* __restrict__ x16, const _Float16* __restrict__ Wt,
    const float* __restrict__ bias, const float* __restrict__ ctx,
    float* __restrict__ scores) {
    constexpr bool DO_STAGE  = (V == 0 || V == 3);
    constexpr bool DO_DSREAD = (V == 0 || V == 1);
    constexpr bool DO_MFMA   = (V == 0 || V == 1 || V == 2);
    constexpr bool DO_SYNC   = (V == 0 || V == 3);

    __shared__ _Float16 As[2][256 * 32];   // 16 KB per buf
    __shared__ _Float16 Bs[2][128 * 32];   // 8 KB per buf

    // grid 2048 = 256 bm x 8 bn; XCD chunk swizzle (bijective 8 x 256)
    const int nb = ((blockIdx.x & 7) << 8) | (blockIdx.x >> 3);
    const int bm = nb >> 3;
    const int bn = nb & 7;
    const int tid = threadIdx.x;
    const int lane = tid & 63;
    const int w = tid >> 6;       // 0..7
    const int wm = w >> 1;        // 0..3
    const int wn = w & 1;         // 0..1

    const int lrow = lane >> 2;                     // 0..15
    const int gslot = (lane & 3) ^ ((lane >> 3) & 3);
    const int gcol = gslot * 8;                     // halves

    const _Float16* Ab = x16 + (size_t)(bm * 256) * KDIM;
    const _Float16* Bb = Wt  + (size_t)(bn * 128) * KDIM;

    floatx4 acc[4][4] = {};

    const int frow = lane & 15;
    const int fslot = ((lane >> 4) ^ ((frow >> 1) & 3)) * 8;   // halves

    #define STAGE(buf, kt)                                                        \
        {                                                                         \
            const int kc = (kt) * 32 + gcol;                                      \
            _Pragma("unroll")                                                     \
            for (int i = 0; i < 2; ++i) {                                         \
                const int j = w + i * 8;                                          \
                GLOAD16(Ab + (size_t)(j * 16 + lrow) * KDIM + kc, &As[buf][j * 512]); \
            }                                                                     \
            GLOAD16(Bb + (size_t)(w * 16 + lrow) * KDIM + kc, &Bs[buf][w * 512]); \
        }

    // synthetic frags for V2 (kept live via lane dependence)
    half8 synthA, synthB;
    #pragma unroll
    for (int i = 0; i < 8; ++i) {
        synthA[i] = (_Float16)(float)((lane + i) & 7);
        synthB[i] = (_Float16)(float)((lane * 2 + i) & 7);
    }

    #define COMPUTE(buf)                                                          \
        {                                                                         \
            half8 afr[4], bfr[4];                                                 \
            if (DO_DSREAD) {                                                      \
                _Pragma("unroll")                                                 \
                for (int m = 0; m < 4; ++m)                                       \
                    afr[m] = *(const half8*)&As[buf][(wm * 64 + m * 16 + frow) * 32 + fslot]; \
                _Pragma("unroll")                                                 \
                for (int n = 0; n < 4; ++n)                                       \
                    bfr[n] = *(const half8*)&Bs[buf][(wn * 64 + n * 16 + frow) * 32 + fslot]; \
            } else {                                                              \
                _Pragma("unroll")                                                 \
                for (int m = 0; m < 4; ++m) afr[m] = synthA;                      \
                _Pragma("unroll")                                                 \
                for (int n = 0; n < 4; ++n) bfr[n] = synthB;                      \
            }                                                                     \
            if (DO_MFMA) {                                                        \
                _Pragma("unroll")                                                 \
                for (int m = 0; m < 4; ++m)                                       \
                    _Pragma("unroll")                                             \
                    for (int n = 0; n < 4; ++n)                                   \
                        acc[m][n] = __builtin_amdgcn_mfma_f32_16x16x32_f16(       \
                            afr[m], bfr[n], acc[m][n], 0, 0, 0);                  \
            } else {                                                              \
                _Pragma("unroll")                                                 \
                for (int m = 0; m < 4; ++m) {                                     \
                    asm volatile("" :: "v"(afr[m]));                              \
                    asm volatile("" :: "v"(bfr[m]));                              \
                }                                                                 \
            }                                                                     \
        }

    if (DO_STAGE) STAGE(0, 0);

    for (int kt = 0; kt < 31; ++kt) {
        const int cur = kt & 1;
        if (DO_STAGE) STAGE(cur ^ 1, kt + 1);
        if (DO_SYNC) {
            asm volatile("s_waitcnt vmcnt(3)" ::: "memory");
            __builtin_amdgcn_sched_barrier(0);
            __builtin_amdgcn_s_barrier();
        }
        COMPUTE(cur);
        if (DO_SYNC) __builtin_amdgcn_s_barrier();
    }
    if (DO_SYNC) {
        asm volatile("s_waitcnt vmcnt(0)" ::: "memory");
        __builtin_amdgcn_sched_barrier(0);
        __builtin_amdgcn_s_barrier();
    }
    COMPUTE(1);

    #undef COMPUTE
    #undef STAGE

    // ---- epilogue: fast tanh + ctx dot + 16-lane reduce + atomic ----
    float bv[4], cv[4];
    #pragma unroll
    for (int n = 0; n < 4; ++n) {
        const int col = bn * 128 + wn * 64 + n * 16 + frow;
        bv[n] = bias[col];
        cv[n] = ctx[col];
    }
    #pragma unroll
    for (int m = 0; m < 4; ++m) {
        #pragma unroll
        for (int j = 0; j < 4; ++j) {
            float partial = 0.0f;
            #pragma unroll
            for (int n = 0; n < 4; ++n) {
                const float v = acc[m][n][j] + bv[n];
                const float e = __expf(2.0f * v);          // tanh(v)=1-2/(e^{2v}+1)
                const float t = 1.0f - 2.0f * __builtin_amdgcn_rcpf(e + 1.0f);
                partial += t * cv[n];
            }
            #pragma unroll
            for (int off = 1; off < 16; off <<= 1)
                partial += __shfl_xor(partial, off, 64);
            if (frow == 0) {
                const int rowg = bm * 256 + wm * 64 + m * 16 + (lane >> 4) * 4 + j;
                atomicAdd(&scores[rowg], partial);
            }
        }
    }
}

// ---------------------------------------------------------------------------
// Fallback GEMM (ws too small): reg-staged fp32 path.
// ---------------------------------------------------------------------------
__global__ __launch_bounds__(256) void score_gemm_f32(
    const float* __restrict__ A32p, const _Float16* __restrict__ Wt,
    const float* __restrict__ bias, const float* __restrict__ ctx,
    float* __restrict__ scores) {
    __shared__ _Float16 As[128 * 64];
    __shared__ _Float16 Bs[128 * 64];

    const int bid = blockIdx.x;
    const int bm = bid >> 3;
    const int bn = bid & 7;
    const int tid = threadIdx.x;
    const int lane = tid & 63;
    const int wid = tid >> 6;
    const int wm = wid >> 1;
    const int wn = wid & 1;

    const int c = tid & 7;
    const int r0 = tid >> 3;
    const int swz = (r0 & 7) << 3;
    const int wcol = (c * 8) ^ swz;

    float4 aF[4][2];
    int4   bR[4];

    #pragma unroll
    for (int i = 0; i < 4; ++i) {
        const int row = r0 + 32 * i;
        const float* p = A32p + (size_t)(bm * 128 + row) * KDIM + c * 8;
        aF[i][0] = *(const float4*)p;
        aF[i][1] = *(const float4*)(p + 4);
        bR[i] = *(const int4*)(Wt + (size_t)(bn * 128 + row) * KDIM + c * 8);
    }

    floatx4 acc[4][4] = {};

    for (int kt = 0; kt < KDIM / 64; ++kt) {
        __syncthreads();
        #pragma unroll
        for (int i = 0; i < 4; ++i) {
            const int row = r0 + 32 * i;
            half8 h;
            h[0] = (_Float16)aF[i][0].x; h[1] = (_Float16)aF[i][0].y;
            h[2] = (_Float16)aF[i][0].z; h[3] = (_Float16)aF[i][0].w;
            h[4] = (_Float16)aF[i][1].x; h[5] = (_Float16)aF[i][1].y;
            h[6] = (_Float16)aF[i][1].z; h[7] = (_Float16)aF[i][1].w;
            *(half8*)&As[row * 64 + wcol] = h;
            *(int4*)&Bs[row * 64 + wcol] = bR[i];
        }
        __syncthreads();

        if (kt + 1 < KDIM / 64) {
            #pragma unroll
            for (int i = 0; i < 4; ++i) {
                const int row = r0 + 32 * i;
                const float* p = A32p + (size_t)(bm * 128 + row) * KDIM + (kt + 1) * 64 + c * 8;
                aF[i][0] = *(const float4*)p;
                aF[i][1] = *(const float4*)(p + 4);
                bR[i] = *(const int4*)(Wt + (size_t)(bn * 128 + row) * KDIM + (kt + 1) * 64 + c * 8);
            }
        }

        #pragma unroll
        for (int s = 0; s < 2; ++s) {
            half8 afr[4], bfr[4];
            const int colr = s * 32 + (lane >> 4) * 8;
            #pragma unroll
            for (int m = 0; m < 4; ++m) {
                const int row = wm * 64 + m * 16 + (lane & 15);
                afr[m] = *(const half8*)&As[row * 64 + (colr ^ ((row & 7) << 3))];
            }
            #pragma unroll
            for (int n = 0; n < 4; ++n) {
                const int row = wn * 64 + n * 16 + (lane & 15);
                bfr[n] = *(const half8*)&Bs[row * 64 + (colr ^ ((row & 7) << 3))];
            }
            #pragma unroll
            for (int m = 0; m < 4; ++m)
                #pragma unroll
                for (int n = 0; n < 4; ++n)
                    acc[m][n] = __builtin_amdgcn_mfma_f32_16x16x32_f16(
                        afr[m], bfr[n], acc[m][n], 0, 0, 0);
        }
    }

    float bv[4], cv[4];
    #pragma unroll
    for (int n = 0; n < 4; ++n) {
        const int col = bn * 128 + wn * 64 + n * 16 + (lane & 15);
        bv[n] = bias[col];
        cv[n] = ctx[col];
    }
    #pragma unroll
    for (int m = 0; m < 4; ++m) {
        #pragma unroll
        for (int j = 0; j < 4; ++j) {
            float partial = 0.0f;
            #pragma unroll
            for (int n = 0; n < 4; ++n) {
                const float v = acc[m][n][j] + bv[n];
                const float e = __expf(2.0f * v);
                const float t = 1.0f - 2.0f * __builtin_amdgcn_rcpf(e + 1.0f);
                partial += t * cv[n];
            }
            #pragma unroll
            for (int off = 1; off < 16; off <<= 1)
                partial += __shfl_xor(partial, off, 64);
            if ((lane & 15) == 0) {
                const int rowg = bm * 128 + wm * 64 + m * 16 + (lane >> 4) * 4 + j;
                atomicAdd(&scores[rowg], partial);
            }
        }
    }
}

// ---------------------------------------------------------------------------
// Kernel 4: softmax over seq dim per batch. 32 blocks x 256 threads.
// ---------------------------------------------------------------------------
__global__ void softmax_kernel(const float* __restrict__ scores,
                               float* __restrict__ weights) {
    const int bb = blockIdx.x;
    const int tid = threadIdx.x;
    const float* s = scores + (size_t)bb * SEQ;
    float* w = weights + (size_t)bb * SEQ;

    __shared__ float red[8];

    float v[8];
    float mx = -1e30f;
    #pragma unroll
    for (int i = 0; i < 8; ++i) {
        v[i] = s[tid + i * 256];
        mx = fmaxf(mx, v[i]);
    }
    #pragma unroll
    for (int off = 1; off < 64; off <<= 1)
        mx = fmaxf(mx, __shfl_xor(mx, off, 64));
    const int wv = tid >> 6;
    if ((tid & 63) == 0) red[wv] = mx;
    __syncthreads();
    mx = fmaxf(fmaxf(red[0], red[1]), fmaxf(red[2], red[3]));

    float sum = 0.0f;
    #pragma unroll
    for (int i = 0; i < 8; ++i) {
        v[i] = __expf(v[i] - mx);
        sum += v[i];
    }
    #pragma unroll
    for (int off = 1; off < 64; off <<= 1)
        sum += __shfl_xor(sum, off, 64);
    if ((tid & 63) == 0) red[4 + wv] = sum;
    __syncthreads();
    sum = red[4] + red[5] + red[6] + red[7];
    const float inv = 1.0f / sum;
    #pragma unroll
    for (int i = 0; i < 8; ++i)
        w[tid + i * 256] = v[i] * inv;
}

// ---------------------------------------------------------------------------
// Kernel 5: weighted pooling (fp32 fallback).
// ---------------------------------------------------------------------------
__global__ __launch_bounds__(256) void pool_kernel(const float* __restrict__ x,
                                                   const float* __restrict__ weights,
                                                   float* __restrict__ out) {
    const int bb = blockIdx.x >> 4;
    const int sc = blockIdx.x & 15;
    const int tid = threadIdx.x;

    const float4* xb = (const float4*)(x + (size_t)bb * SEQ * EMBED) +
                       (size_t)(sc * 128) * (EMBED / 4) + tid;
    const float* wb = weights + (size_t)bb * SEQ + sc * 128;

    float ax = 0.f, ay = 0.f, az = 0.f, aw = 0.f;
    #pragma unroll 4
    for (int s = 0; s < 128; ++s) {
        const float wgt = wb[s];
        const float4 xv = xb[(size_t)s * (EMBED / 4)];
        ax += wgt * xv.x; ay += wgt * xv.y; az += wgt * xv.z; aw += wgt * xv.w;
    }
    float* o = out + (size_t)bb * EMBED + tid * 4;
    atomicAdd(o + 0, ax);
    atomicAdd(o + 1, ay);
    atomicAdd(o + 2, az);
    atomicAdd(o + 3, aw);
}

// ---------------------------------------------------------------------------
// Kernel 5b: weighted pooling (fp16 x16) — halves the read bytes.
// ---------------------------------------------------------------------------
__global__ __launch_bounds__(256) void pool16_kernel(const _Float16* __restrict__ x16,
                                                     const float* __restrict__ weights,
                                                     float* __restrict__ out) {
    const int bb = blockIdx.x >> 4;
    const int sc = blockIdx.x & 15;
    const int tid = threadIdx.x;

    const _Float16* xb = x16 + (size_t)bb * SEQ * EMBED +
                         (size_t)(sc * 128) * EMBED + tid * 4;
    const float* wb = weights + (size_t)bb * SEQ + sc * 128;

    float ax = 0.f, ay = 0.f, az = 0.f, aw = 0.f;
    #pragma unroll 4
    for (int s = 0; s < 128; ++s) {
        const float wgt = wb[s];
        const half4 h = *(const half4*)(xb + (size_t)s * EMBED);
        ax += wgt * (float)h[0]; ay += wgt * (float)h[1];
        az += wgt * (float)h[2]; aw += wgt * (float)h[3];
    }
    float* o = out + (size_t)bb * EMBED + tid * 4;
    atomicAdd(o + 0, ax);
    atomicAdd(o + 1, ay);
    atomicAdd(o + 2, az);
    atomicAdd(o + 3, aw);
}

// ---------------------------------------------------------------------------
extern "C" void kernel_launch(void* const* d_in, const int* in_sizes, int n_in,
                              void* d_out, int out_size, void* d_ws, size_t ws_size,
                              hipStream_t stream) {
    const float* x   = (const float*)d_in[0];
    const float* W   = (const float*)d_in[1];
    const float* b   = (const float*)d_in[2];
    const float* ctx = (const float*)d_in[3];
    float* out = (float*)d_out;

    char* ws = (char*)d_ws;
    _Float16* Wt      = (_Float16*)ws;                               // 2 MB
    float*    scores  = (float*)(ws + (2u << 20));                   // 256 KB
    float*    weights = (float*)(ws + (2u << 20) + (256u << 10));    // 256 KB
    float*    scratch = (float*)(ws + (2u << 20) + (512u << 10));    // 256 KB (ablation sink)
    _Float16* x16     = (_Float16*)(ws + (4u << 20));                // 128 MB

    const size_t need = (4ull << 20) + ((size_t)M_TOT * KDIM * 2);
    const bool fast = ws_size >= need;

    hipLaunchKernelGGL(zero_kernel, dim3(M_TOT / 256), dim3(256), 0, stream, scores, out);
    hipLaunchKernelGGL(transpose_w_kernel, dim3(32, 32), dim3(32, 8), 0, stream, W, Wt);

    if (fast) {
        hipLaunchKernelGGL(cvt_x_kernel, dim3(4096), dim3(256), 0, stream, x, x16);
        // --- ablation probes (outputs -> scratch; timing via rocprof) ---
        hipLaunchKernelGGL((score_gemm_abl<2>), dim3(2048), dim3(512), 0, stream,
                           x16, Wt, b, ctx, scratch);   // MFMA floor
        hipLaunchKernelGGL((score_gemm_abl<1>), dim3(2048), dim3(512), 0, stream,
                           x16, Wt, b, ctx, scratch);   // ds_read + MFMA
        hipLaunchKernelGGL((score_gemm_abl<3>), dim3(2048), dim3(512), 0, stream,
                           x16, Wt, b, ctx, scratch);   // stage + sync only
        // --- the real GEMM ---
        hipLaunchKernelGGL((score_gemm_abl<0>), dim3(2048), dim3(512), 0, stream,
                           x16, Wt, b, ctx, scores);
    } else {
        hipLaunchKernelGGL(score_gemm_f32, dim3(4096), dim3(256), 0, stream,
                           x, Wt, b, ctx, scores);
    }

    hipLaunchKernelGGL(softmax_kernel, dim3(BATCH), dim3(256), 0, stream, scores, weights);

    if (fast) {
        hipLaunchKernelGGL(pool16_kernel, dim3(BATCH * 16), dim3(256), 0, stream,
                           x16, weights, out);
    } else {
        hipLaunchKernelGGL(pool_kernel, dim3(BATCH * 16), dim3(256), 0, stream,
                           x, weights, out);
    }
}

// Round 18
// 353.741 us; speedup vs baseline: 1.5575x; 1.5575x over previous
//
#include <hip/hip_runtime.h>
#include <hip/hip_bf16.h>

typedef _Float16 half8 __attribute__((ext_vector_type(8)));
typedef _Float16 half4 __attribute__((ext_vector_type(4)));
typedef float floatx4 __attribute__((ext_vector_type(4)));

#define EMBED 1024
#define SEQ   2048
#define BATCH 32
#define M_TOT (BATCH * SEQ)   // 65536 rows
#define KDIM  1024
#define NDIM  1024

// async global->LDS, 16B per lane, dest = wave-uniform base + lane*16
#define GLOAD16(g, l) __builtin_amdgcn_global_load_lds(                      \
    (const __attribute__((address_space(1))) void*)(g),                      \
    (__attribute__((address_space(3))) void*)(l), 16, 0, 0)

// ---------------------------------------------------------------------------
// Kernel 1: transpose + convert W[K][N] fp32 -> Wt[N][K] fp16
// ---------------------------------------------------------------------------
__global__ void transpose_w_kernel(const float* __restrict__ W,
                                   _Float16* __restrict__ Wt) {
    __shared__ float t[32][33];
    const int kt = blockIdx.x * 32;
    const int nt = blockIdx.y * 32;
    #pragma unroll
    for (int i = 0; i < 4; ++i)
        t[threadIdx.y + 8 * i][threadIdx.x] =
            W[(size_t)(kt + threadIdx.y + 8 * i) * NDIM + nt + threadIdx.x];
    __syncthreads();
    #pragma unroll
    for (int i = 0; i < 4; ++i)
        Wt[(size_t)(nt + threadIdx.y + 8 * i) * KDIM + kt + threadIdx.x] =
            (_Float16)t[threadIdx.x][threadIdx.y + 8 * i];
}

// ---------------------------------------------------------------------------
// Kernel 2: zero scores + out
// ---------------------------------------------------------------------------
__global__ void zero_kernel(float* __restrict__ scores, float* __restrict__ out) {
    const int i = blockIdx.x * 256 + threadIdx.x;
    if (i < M_TOT) scores[i] = 0.0f;
    if (i < BATCH * EMBED) out[i] = 0.0f;
}

// ---------------------------------------------------------------------------
// Kernel 2b: convert x fp32 -> fp16 (64M elements)
// ---------------------------------------------------------------------------
__global__ __launch_bounds__(256) void cvt_x_kernel(const float* __restrict__ x,
                                                    _Float16* __restrict__ x16) {
    const size_t stride = (size_t)gridDim.x * 256 * 8;
    for (size_t i = ((size_t)blockIdx.x * 256 + threadIdx.x) * 8;
         i < (size_t)M_TOT * KDIM; i += stride) {
        const float4 a = *(const float4*)(x + i);
        const float4 b = *(const float4*)(x + i + 4);
        half8 h;
        h[0] = (_Float16)a.x; h[1] = (_Float16)a.y; h[2] = (_Float16)a.z; h[3] = (_Float16)a.w;
        h[4] = (_Float16)b.x; h[5] = (_Float16)b.y; h[6] = (_Float16)b.z; h[7] = (_Float16)b.w;
        *(half8*)(x16 + i) = h;
    }
}

// ---------------------------------------------------------------------------
// Kernel 3: fused scores GEMM — r10 kernel + DEPTH-3 RING (the clean depth test).
// BM=128, BN=128, BK=32, 256 threads (2x2 waves, 64x64 wave-tile),
// mfma_f32_16x16x32_f16, gload_lds(16B), r10's verified conflict-free swizzle.
// Ablation (r17) showed compute-complex and staging-complex are ADDITIVE:
// depth-1 staging gives only ~1 iteration (~250cy) of cover vs ~600cy L3
// latency -> ~350cy stall per K-step that barriers prevent hiding.
// Fix: LDS ring of 4 tile-buffers (64 KB -> 2 blocks/CU); stage tile kt+3
// each iteration (cover = 3 iterations >= latency).  Issue strictly
// tile-ordered, 4 loads/wave/tile -> steady-state s_waitcnt vmcnt(12)
// (tiles kt+1..kt+3 stay in flight); tail peels 8/4/0.  Raw s_barrier only.
// ---------------------------------------------------------------------------
__global__ __launch_bounds__(256, 2) void score_gemm15(
    const _Float16* __restrict__ x16, const _Float16* __restrict__ Wt,
    const float* __restrict__ bias, const float* __restrict__ ctx,
    float* __restrict__ scores) {
    __shared__ _Float16 As[4][128 * 32];   // 8 KB per buf
    __shared__ _Float16 Bs[4][128 * 32];   // 8 KB per buf  (total 64 KB)

    // XCD-aware chunk swizzle (4096 blocks, 8 XCDs, bijective)
    const int nb = ((blockIdx.x & 7) << 9) | (blockIdx.x >> 3);
    const int bm = nb >> 3;       // 512 row tiles, contiguous per XCD
    const int bn = nb & 7;        // 8 col tiles, innermost per XCD
    const int tid = threadIdx.x;
    const int lane = tid & 63;
    const int wid = tid >> 6;
    const int wm = wid >> 1;
    const int wn = wid & 1;

    // staging (r10-verified): instr j covers rows j*16..j*16+15; wave w owns
    // j in {2w, 2w+1} for both A and B (4 loads/wave/tile).
    // lane l -> row j*16+(l>>2), LDS slot l&3 linear; global 16B slot
    // pre-swizzled g = (l&3) ^ ((l>>3)&3)  [= (row>>1)&3, both-sides].
    const int jA0 = wid * 2;
    const int lrow = lane >> 2;                     // 0..15
    const int gslot = (lane & 3) ^ ((lane >> 3) & 3);
    const int gcol = gslot * 8;                     // halves

    const _Float16* Ab = x16 + (size_t)(bm * 128) * KDIM;
    const _Float16* Bb = Wt  + (size_t)(bn * 128) * KDIM;

    floatx4 acc[4][4] = {};

    // frag read (r10-verified, 0 conflicts): physical slot = (lane>>4) ^ ((frow>>1)&3)
    const int frow = lane & 15;
    const int fslot = ((lane >> 4) ^ ((frow >> 1) & 3)) * 8;   // halves

    #define STAGE(buf, kt)                                                        \
        {                                                                         \
            const int kc = (kt) * 32 + gcol;                                      \
            _Pragma("unroll")                                                     \
            for (int i = 0; i < 2; ++i) {                                         \
                const int j = jA0 + i;                                            \
                GLOAD16(Ab + (size_t)(j * 16 + lrow) * KDIM + kc, &As[buf][j * 512]); \
                GLOAD16(Bb + (size_t)(j * 16 + lrow) * KDIM + kc, &Bs[buf][j * 512]); \
            }                                                                     \
        }

    #define COMPUTE(buf)                                                          \
        {                                                                         \
            half8 afr[4], bfr[4];                                                 \
            _Pragma("unroll")                                                     \
            for (int m = 0; m < 4; ++m)                                           \
                afr[m] = *(const half8*)&As[buf][(wm * 64 + m * 16 + frow) * 32 + fslot]; \
            _Pragma("unroll")                                                     \
            for (int n = 0; n < 4; ++n)                                           \
                bfr[n] = *(const half8*)&Bs[buf][(wn * 64 + n * 16 + frow) * 32 + fslot]; \
            __builtin_amdgcn_s_setprio(1);                                        \
            _Pragma("unroll")                                                     \
            for (int m = 0; m < 4; ++m)                                           \
                _Pragma("unroll")                                                 \
                for (int n = 0; n < 4; ++n)                                       \
                    acc[m][n] = __builtin_amdgcn_mfma_f32_16x16x32_f16(           \
                        afr[m], bfr[n], acc[m][n], 0, 0, 0);                      \
            __builtin_amdgcn_s_setprio(0);                                        \
        }

    // prologue: stage tiles 0,1,2 (12 loads/wave in flight, tile-ordered)
    STAGE(0, 0);
    STAGE(1, 1);
    STAGE(2, 2);

    // main: kt = 0..28 stages tile kt+3 and computes tile kt.
    // Steady state after issue: tiles kt..kt+3 outstanding (16 loads);
    // vmcnt(12) completes tile kt, keeps kt+1..kt+3 in flight.
    for (int kt = 0; kt < 29; ++kt) {
        STAGE((kt + 3) & 3, kt + 3);
        asm volatile("s_waitcnt vmcnt(12)" ::: "memory");
        __builtin_amdgcn_sched_barrier(0);
        __builtin_amdgcn_s_barrier();           // tile kt visible block-wide
        COMPUTE(kt & 3);
        __builtin_amdgcn_s_barrier();           // reads done; buf (kt&3) reusable
    }
    // kt = 29: tiles 30,31 in flight (8 loads)
    asm volatile("s_waitcnt vmcnt(8)" ::: "memory");
    __builtin_amdgcn_sched_barrier(0);
    __builtin_amdgcn_s_barrier();
    COMPUTE(1);
    __builtin_amdgcn_s_barrier();
    // kt = 30: tile 31 in flight (4 loads)
    asm volatile("s_waitcnt vmcnt(4)" ::: "memory");
    __builtin_amdgcn_sched_barrier(0);
    __builtin_amdgcn_s_barrier();
    COMPUTE(2);
    __builtin_amdgcn_s_barrier();
    // kt = 31: drain
    asm volatile("s_waitcnt vmcnt(0)" ::: "memory");
    __builtin_amdgcn_sched_barrier(0);
    __builtin_amdgcn_s_barrier();
    COMPUTE(3);

    #undef COMPUTE
    #undef STAGE

    // ---- epilogue: fast tanh + ctx dot + 16-lane reduce + atomic ----
    float bv[4], cv[4];
    #pragma unroll
    for (int n = 0; n < 4; ++n) {
        const int col = bn * 128 + wn * 64 + n * 16 + (lane & 15);
        bv[n] = bias[col];
        cv[n] = ctx[col];
    }
    #pragma unroll
    for (int m = 0; m < 4; ++m) {
        #pragma unroll
        for (int j = 0; j < 4; ++j) {
            float partial = 0.0f;
            #pragma unroll
            for (int n = 0; n < 4; ++n) {
                const float v = acc[m][n][j] + bv[n];
                const float e = __expf(2.0f * v);          // tanh(v)=1-2/(e^{2v}+1)
                const float t = 1.0f - 2.0f * __builtin_amdgcn_rcpf(e + 1.0f);
                partial += t * cv[n];
            }
            #pragma unroll
            for (int off = 1; off < 16; off <<= 1)
                partial += __shfl_xor(partial, off, 64);
            if ((lane & 15) == 0) {
                const int rowg = bm * 128 + wm * 64 + m * 16 + (lane >> 4) * 4 + j;
                atomicAdd(&scores[rowg], partial);
            }
        }
    }
}

// ---------------------------------------------------------------------------
// Fallback GEMM (ws too small): reg-staged fp32 path.
// ---------------------------------------------------------------------------
__global__ __launch_bounds__(256) void score_gemm_f32(
    const float* __restrict__ A32p, const _Float16* __restrict__ Wt,
    const float* __restrict__ bias, const float* __restrict__ ctx,
    float* __restrict__ scores) {
    __shared__ _Float16 As[128 * 64];
    __shared__ _Float16 Bs[128 * 64];

    const int bid = blockIdx.x;
    const int bm = bid >> 3;
    const int bn = bid & 7;
    const int tid = threadIdx.x;
    const int lane = tid & 63;
    const int wid = tid >> 6;
    const int wm = wid >> 1;
    const int wn = wid & 1;

    const int c = tid & 7;
    const int r0 = tid >> 3;
    const int swz = (r0 & 7) << 3;
    const int wcol = (c * 8) ^ swz;

    float4 aF[4][2];
    int4   bR[4];

    #pragma unroll
    for (int i = 0; i < 4; ++i) {
        const int row = r0 + 32 * i;
        const float* p = A32p + (size_t)(bm * 128 + row) * KDIM + c * 8;
        aF[i][0] = *(const float4*)p;
        aF[i][1] = *(const float4*)(p + 4);
        bR[i] = *(const int4*)(Wt + (size_t)(bn * 128 + row) * KDIM + c * 8);
    }

    floatx4 acc[4][4] = {};

    for (int kt = 0; kt < KDIM / 64; ++kt) {
        __syncthreads();
        #pragma unroll
        for (int i = 0; i < 4; ++i) {
            const int row = r0 + 32 * i;
            half8 h;
            h[0] = (_Float16)aF[i][0].x; h[1] = (_Float16)aF[i][0].y;
            h[2] = (_Float16)aF[i][0].z; h[3] = (_Float16)aF[i][0].w;
            h[4] = (_Float16)aF[i][1].x; h[5] = (_Float16)aF[i][1].y;
            h[6] = (_Float16)aF[i][1].z; h[7] = (_Float16)aF[i][1].w;
            *(half8*)&As[row * 64 + wcol] = h;
            *(int4*)&Bs[row * 64 + wcol] = bR[i];
        }
        __syncthreads();

        if (kt + 1 < KDIM / 64) {
            #pragma unroll
            for (int i = 0; i < 4; ++i) {
                const int row = r0 + 32 * i;
                const float* p = A32p + (size_t)(bm * 128 + row) * KDIM + (kt + 1) * 64 + c * 8;
                aF[i][0] = *(const float4*)p;
                aF[i][1] = *(const float4*)(p + 4);
                bR[i] = *(const int4*)(Wt + (size_t)(bn * 128 + row) * KDIM + (kt + 1) * 64 + c * 8);
            }
        }

        #pragma unroll
        for (int s = 0; s < 2; ++s) {
            half8 afr[4], bfr[4];
            const int colr = s * 32 + (lane >> 4) * 8;
            #pragma unroll
            for (int m = 0; m < 4; ++m) {
                const int row = wm * 64 + m * 16 + (lane & 15);
                afr[m] = *(const half8*)&As[row * 64 + (colr ^ ((row & 7) << 3))];
            }
            #pragma unroll
            for (int n = 0; n < 4; ++n) {
                const int row = wn * 64 + n * 16 + (lane & 15);
                bfr[n] = *(const half8*)&Bs[row * 64 + (colr ^ ((row & 7) << 3))];
            }
            #pragma unroll
            for (int m = 0; m < 4; ++m)
                #pragma unroll
                for (int n = 0; n < 4; ++n)
                    acc[m][n] = __builtin_amdgcn_mfma_f32_16x16x32_f16(
                        afr[m], bfr[n], acc[m][n], 0, 0, 0);
        }
    }

    float bv[4], cv[4];
    #pragma unroll
    for (int n = 0; n < 4; ++n) {
        const int col = bn * 128 + wn * 64 + n * 16 + (lane & 15);
        bv[n] = bias[col];
        cv[n] = ctx[col];
    }
    #pragma unroll
    for (int m = 0; m < 4; ++m) {
        #pragma unroll
        for (int j = 0; j < 4; ++j) {
            float partial = 0.0f;
            #pragma unroll
            for (int n = 0; n < 4; ++n) {
                const float v = acc[m][n][j] + bv[n];
                const float e = __expf(2.0f * v);
                const float t = 1.0f - 2.0f * __builtin_amdgcn_rcpf(e + 1.0f);
                partial += t * cv[n];
            }
            #pragma unroll
            for (int off = 1; off < 16; off <<= 1)
                partial += __shfl_xor(partial, off, 64);
            if ((lane & 15) == 0) {
                const int rowg = bm * 128 + wm * 64 + m * 16 + (lane >> 4) * 4 + j;
                atomicAdd(&scores[rowg], partial);
            }
        }
    }
}

// ---------------------------------------------------------------------------
// Kernel 4: softmax over seq dim per batch. 32 blocks x 256 threads.
// ---------------------------------------------------------------------------
__global__ void softmax_kernel(const float* __restrict__ scores,
                               float* __restrict__ weights) {
    const int bb = blockIdx.x;
    const int tid = threadIdx.x;
    const float* s = scores + (size_t)bb * SEQ;
    float* w = weights + (size_t)bb * SEQ;

    __shared__ float red[8];

    float v[8];
    float mx = -1e30f;
    #pragma unroll
    for (int i = 0; i < 8; ++i) {
        v[i] = s[tid + i * 256];
        mx = fmaxf(mx, v[i]);
    }
    #pragma unroll
    for (int off = 1; off < 64; off <<= 1)
        mx = fmaxf(mx, __shfl_xor(mx, off, 64));
    const int wv = tid >> 6;
    if ((tid & 63) == 0) red[wv] = mx;
    __syncthreads();
    mx = fmaxf(fmaxf(red[0], red[1]), fmaxf(red[2], red[3]));

    float sum = 0.0f;
    #pragma unroll
    for (int i = 0; i < 8; ++i) {
        v[i] = __expf(v[i] - mx);
        sum += v[i];
    }
    #pragma unroll
    for (int off = 1; off < 64; off <<= 1)
        sum += __shfl_xor(sum, off, 64);
    if ((tid & 63) == 0) red[4 + wv] = sum;
    __syncthreads();
    sum = red[4] + red[5] + red[6] + red[7];
    const float inv = 1.0f / sum;
    #pragma unroll
    for (int i = 0; i < 8; ++i)
        w[tid + i * 256] = v[i] * inv;
}

// ---------------------------------------------------------------------------
// Kernel 5: weighted pooling (fp32 fallback).
// ---------------------------------------------------------------------------
__global__ __launch_bounds__(256) void pool_kernel(const float* __restrict__ x,
                                                   const float* __restrict__ weights,
                                                   float* __restrict__ out) {
    const int bb = blockIdx.x >> 4;
    const int sc = blockIdx.x & 15;
    const int tid = threadIdx.x;

    const float4* xb = (const float4*)(x + (size_t)bb * SEQ * EMBED) +
                       (size_t)(sc * 128) * (EMBED / 4) + tid;
    const float* wb = weights + (size_t)bb * SEQ + sc * 128;

    float ax = 0.f, ay = 0.f, az = 0.f, aw = 0.f;
    #pragma unroll 4
    for (int s = 0; s < 128; ++s) {
        const float wgt = wb[s];
        const float4 xv = xb[(size_t)s * (EMBED / 4)];
        ax += wgt * xv.x; ay += wgt * xv.y; az += wgt * xv.z; aw += wgt * xv.w;
    }
    float* o = out + (size_t)bb * EMBED + tid * 4;
    atomicAdd(o + 0, ax);
    atomicAdd(o + 1, ay);
    atomicAdd(o + 2, az);
    atomicAdd(o + 3, aw);
}

// ---------------------------------------------------------------------------
// Kernel 5b: weighted pooling (fp16 x16) — halves the read bytes.
// ---------------------------------------------------------------------------
__global__ __launch_bounds__(256) void pool16_kernel(const _Float16* __restrict__ x16,
                                                     const float* __restrict__ weights,
                                                     float* __restrict__ out) {
    const int bb = blockIdx.x >> 4;
    const int sc = blockIdx.x & 15;
    const int tid = threadIdx.x;

    const _Float16* xb = x16 + (size_t)bb * SEQ * EMBED +
                         (size_t)(sc * 128) * EMBED + tid * 4;
    const float* wb = weights + (size_t)bb * SEQ + sc * 128;

    float ax = 0.f, ay = 0.f, az = 0.f, aw = 0.f;
    #pragma unroll 4
    for (int s = 0; s < 128; ++s) {
        const float wgt = wb[s];
        const half4 h = *(const half4*)(xb + (size_t)s * EMBED);
        ax += wgt * (float)h[0]; ay += wgt * (float)h[1];
        az += wgt * (float)h[2]; aw += wgt * (float)h[3];
    }
    float* o = out + (size_t)bb * EMBED + tid * 4;
    atomicAdd(o + 0, ax);
    atomicAdd(o + 1, ay);
    atomicAdd(o + 2, az);
    atomicAdd(o + 3, aw);
}

// ---------------------------------------------------------------------------
extern "C" void kernel_launch(void* const* d_in, const int* in_sizes, int n_in,
                              void* d_out, int out_size, void* d_ws, size_t ws_size,
                              hipStream_t stream) {
    const float* x   = (const float*)d_in[0];
    const float* W   = (const float*)d_in[1];
    const float* b   = (const float*)d_in[2];
    const float* ctx = (const float*)d_in[3];
    float* out = (float*)d_out;

    char* ws = (char*)d_ws;
    _Float16* Wt      = (_Float16*)ws;                               // 2 MB
    float*    scores  = (float*)(ws + (2u << 20));                   // 256 KB
    float*    weights = (float*)(ws + (2u << 20) + (256u << 10));    // 256 KB
    _Float16* x16     = (_Float16*)(ws + (4u << 20));                // 128 MB

    const size_t need = (4ull << 20) + ((size_t)M_TOT * KDIM * 2);
    const bool fast = ws_size >= need;

    hipLaunchKernelGGL(zero_kernel, dim3(M_TOT / 256), dim3(256), 0, stream, scores, out);
    hipLaunchKernelGGL(transpose_w_kernel, dim3(32, 32), dim3(32, 8), 0, stream, W, Wt);

    if (fast) {
        hipLaunchKernelGGL(cvt_x_kernel, dim3(4096), dim3(256), 0, stream, x, x16);
        hipLaunchKernelGGL(score_gemm15, dim3(4096), dim3(256), 0, stream,
                           x16, Wt, b, ctx, scores);
    } else {
        hipLaunchKernelGGL(score_gemm_f32, dim3(4096), dim3(256), 0, stream,
                           x, Wt, b, ctx, scores);
    }

    hipLaunchKernelGGL(softmax_kernel, dim3(BATCH), dim3(256), 0, stream, scores, weights);

    if (fast) {
        hipLaunchKernelGGL(pool16_kernel, dim3(BATCH * 16), dim3(256), 0, stream,
                           x16, weights, out);
    } else {
        hipLaunchKernelGGL(pool_kernel, dim3(BATCH * 16), dim3(256), 0, stream,
                           x, weights, out);
    }
}

// Round 20
// 287.234 us; speedup vs baseline: 1.9182x; 1.2315x over previous
//
#include <hip/hip_runtime.h>
#include <hip/hip_bf16.h>

typedef _Float16 half8 __attribute__((ext_vector_type(8)));
typedef _Float16 half4 __attribute__((ext_vector_type(4)));
typedef float floatx4 __attribute__((ext_vector_type(4)));

#define EMBED 1024
#define SEQ   2048
#define BATCH 32
#define M_TOT (BATCH * SEQ)   // 65536 rows
#define KDIM  1024
#define NDIM  1024

// async global->LDS, 16B per lane, dest = wave-uniform base + lane*16
#define GLOAD16(g, l) __builtin_amdgcn_global_load_lds(                      \
    (const __attribute__((address_space(1))) void*)(g),                      \
    (__attribute__((address_space(3))) void*)(l), 16, 0, 0)

// ---------------------------------------------------------------------------
// Kernel 1: transpose + convert W[K][N] fp32 -> Wt[N][K] fp16
// ---------------------------------------------------------------------------
__global__ void transpose_w_kernel(const float* __restrict__ W,
                                   _Float16* __restrict__ Wt) {
    __shared__ float t[32][33];
    const int kt = blockIdx.x * 32;
    const int nt = blockIdx.y * 32;
    #pragma unroll
    for (int i = 0; i < 4; ++i)
        t[threadIdx.y + 8 * i][threadIdx.x] =
            W[(size_t)(kt + threadIdx.y + 8 * i) * NDIM + nt + threadIdx.x];
    __syncthreads();
    #pragma unroll
    for (int i = 0; i < 4; ++i)
        Wt[(size_t)(nt + threadIdx.y + 8 * i) * KDIM + kt + threadIdx.x] =
            (_Float16)t[threadIdx.x][threadIdx.y + 8 * i];
}

// ---------------------------------------------------------------------------
// Kernel 2: zero scores + out
// ---------------------------------------------------------------------------
__global__ void zero_kernel(float* __restrict__ scores, float* __restrict__ out) {
    const int i = blockIdx.x * 256 + threadIdx.x;
    if (i < M_TOT) scores[i] = 0.0f;
    if (i < BATCH * EMBED) out[i] = 0.0f;
}

// ---------------------------------------------------------------------------
// Kernel 2b: convert x fp32 -> fp16 (64M elements)
// ---------------------------------------------------------------------------
__global__ __launch_bounds__(256) void cvt_x_kernel(const float* __restrict__ x,
                                                    _Float16* __restrict__ x16) {
    const size_t stride = (size_t)gridDim.x * 256 * 8;
    for (size_t i = ((size_t)blockIdx.x * 256 + threadIdx.x) * 8;
         i < (size_t)M_TOT * KDIM; i += stride) {
        const float4 a = *(const float4*)(x + i);
        const float4 b = *(const float4*)(x + i + 4);
        half8 h;
        h[0] = (_Float16)a.x; h[1] = (_Float16)a.y; h[2] = (_Float16)a.z; h[3] = (_Float16)a.w;
        h[4] = (_Float16)b.x; h[5] = (_Float16)b.y; h[6] = (_Float16)b.z; h[7] = (_Float16)b.w;
        *(half8*)(x16 + i) = h;
    }
}

// ---------------------------------------------------------------------------
// Kernel 3: fused scores GEMM — r16 (best measured: 283.8 us total, passed).
// BM=256, BN=128, BK=32, 512 threads = 8 waves (4M x 2N), wave tile 64x64,
// mfma_f32_16x16x32_f16.
//   A: 16 KB/K-step via gload_lds (2 instr/wave), B: 8 KB via gload_lds
//   (1 instr/wave) — B read by both wn-waves from LDS (no duplication).
// Counted vmcnt(3) (3 loads/wave/tile in flight), raw barriers, verified
// conflict-free swizzle for 64B rows: phys = s ^ ((row>>1)&3), staged via
// pre-swizzled global slot g = (l&3)^((l>>3)&3)  [r10: conflicts == 0].
// LDS 48 KB -> ~3 blocks/CU.
// ---------------------------------------------------------------------------
__global__ __launch_bounds__(512, 4) void score_gemm14(
    const _Float16* __restrict__ x16, const _Float16* __restrict__ Wt,
    const float* __restrict__ bias, const float* __restrict__ ctx,
    float* __restrict__ scores) {
    __shared__ _Float16 As[2][256 * 32];   // 16 KB per buf
    __shared__ _Float16 Bs[2][128 * 32];   // 8 KB per buf

    // grid 2048 = 256 bm x 8 bn; XCD chunk swizzle (bijective: 8 x 256)
    const int nb = ((blockIdx.x & 7) << 8) | (blockIdx.x >> 3);
    const int bm = nb >> 3;       // 0..255, contiguous per XCD
    const int bn = nb & 7;        // 0..7, innermost (A-panel L2/L3 reuse)
    const int tid = threadIdx.x;
    const int lane = tid & 63;
    const int w = tid >> 6;       // 0..7
    const int wm = w >> 1;        // 0..3 (64-row group)
    const int wn = w & 1;         // 0..1 (64-col group)

    // staging: instr j covers rows j*16..j*16+15 (1 KB).  A: 16 instrs,
    // wave w owns {w, w+8}.  B: 8 instrs, wave w owns {w}.
    // lane l -> row j*16 + (l>>2), LDS slot l&3 linear; global 16B slot
    // pre-swizzled g = (l&3) ^ ((l>>3)&3)  [= (row>>1)&3].
    const int lrow = lane >> 2;                     // 0..15
    const int gslot = (lane & 3) ^ ((lane >> 3) & 3);
    const int gcol = gslot * 8;                     // halves

    const _Float16* Ab = x16 + (size_t)(bm * 256) * KDIM;
    const _Float16* Bb = Wt  + (size_t)(bn * 128) * KDIM;

    floatx4 acc[4][4] = {};

    // frag read: row = base + frow, logical slot s = lane>>4,
    // physical p = s ^ ((frow>>1)&3)   [0 conflicts measured, r10/r11]
    const int frow = lane & 15;
    const int fslot = ((lane >> 4) ^ ((frow >> 1) & 3)) * 8;   // halves

    #define STAGE(buf, kt)                                                        \
        {                                                                         \
            const int kc = (kt) * 32 + gcol;                                      \
            _Pragma("unroll")                                                     \
            for (int i = 0; i < 2; ++i) {                                         \
                const int j = w + i * 8;                                          \
                GLOAD16(Ab + (size_t)(j * 16 + lrow) * KDIM + kc, &As[buf][j * 512]); \
            }                                                                     \
            GLOAD16(Bb + (size_t)(w * 16 + lrow) * KDIM + kc, &Bs[buf][w * 512]); \
        }

    #define COMPUTE(buf)                                                          \
        {                                                                         \
            half8 afr[4], bfr[4];                                                 \
            _Pragma("unroll")                                                     \
            for (int m = 0; m < 4; ++m)                                           \
                afr[m] = *(const half8*)&As[buf][(wm * 64 + m * 16 + frow) * 32 + fslot]; \
            _Pragma("unroll")                                                     \
            for (int n = 0; n < 4; ++n)                                           \
                bfr[n] = *(const half8*)&Bs[buf][(wn * 64 + n * 16 + frow) * 32 + fslot]; \
            _Pragma("unroll")                                                     \
            for (int m = 0; m < 4; ++m)                                           \
                _Pragma("unroll")                                                 \
                for (int n = 0; n < 4; ++n)                                       \
                    acc[m][n] = __builtin_amdgcn_mfma_f32_16x16x32_f16(           \
                        afr[m], bfr[n], acc[m][n], 0, 0, 0);                      \
        }

    STAGE(0, 0);               // 3 loads/wave in flight (tile 0)

    for (int kt = 0; kt < 31; ++kt) {
        const int cur = kt & 1;
        STAGE(cur ^ 1, kt + 1);                 // +3 -> 6 in flight
        asm volatile("s_waitcnt vmcnt(3)" ::: "memory");  // tile kt done; kt+1 stays
        __builtin_amdgcn_sched_barrier(0);
        __builtin_amdgcn_s_barrier();           // block-wide: tile kt ready
        COMPUTE(cur);
        __builtin_amdgcn_s_barrier();           // reads done; buf reusable
    }
    // kt = 31 (cur = 1): drain the last 3
    asm volatile("s_waitcnt vmcnt(0)" ::: "memory");
    __builtin_amdgcn_sched_barrier(0);
    __builtin_amdgcn_s_barrier();
    COMPUTE(1);

    #undef COMPUTE
    #undef STAGE

    // ---- epilogue: fast tanh + ctx dot + 16-lane reduce + atomic ----
    float bv[4], cv[4];
    #pragma unroll
    for (int n = 0; n < 4; ++n) {
        const int col = bn * 128 + wn * 64 + n * 16 + frow;
        bv[n] = bias[col];
        cv[n] = ctx[col];
    }
    #pragma unroll
    for (int m = 0; m < 4; ++m) {
        #pragma unroll
        for (int j = 0; j < 4; ++j) {
            float partial = 0.0f;
            #pragma unroll
            for (int n = 0; n < 4; ++n) {
                const float v = acc[m][n][j] + bv[n];
                const float e = __expf(2.0f * v);          // tanh(v)=1-2/(e^{2v}+1)
                const float t = 1.0f - 2.0f * __builtin_amdgcn_rcpf(e + 1.0f);
                partial += t * cv[n];
            }
            #pragma unroll
            for (int off = 1; off < 16; off <<= 1)
                partial += __shfl_xor(partial, off, 64);
            if (frow == 0) {
                const int rowg = bm * 256 + wm * 64 + m * 16 + (lane >> 4) * 4 + j;
                atomicAdd(&scores[rowg], partial);
            }
        }
    }
}

// ---------------------------------------------------------------------------
// Fallback GEMM (ws too small): reg-staged fp32 path.
// ---------------------------------------------------------------------------
__global__ __launch_bounds__(256) void score_gemm_f32(
    const float* __restrict__ A32p, const _Float16* __restrict__ Wt,
    const float* __restrict__ bias, const float* __restrict__ ctx,
    float* __restrict__ scores) {
    __shared__ _Float16 As[128 * 64];
    __shared__ _Float16 Bs[128 * 64];

    const int bid = blockIdx.x;
    const int bm = bid >> 3;
    const int bn = bid & 7;
    const int tid = threadIdx.x;
    const int lane = tid & 63;
    const int wid = tid >> 6;
    const int wm = wid >> 1;
    const int wn = wid & 1;

    const int c = tid & 7;
    const int r0 = tid >> 3;
    const int swz = (r0 & 7) << 3;
    const int wcol = (c * 8) ^ swz;

    float4 aF[4][2];
    int4   bR[4];

    #pragma unroll
    for (int i = 0; i < 4; ++i) {
        const int row = r0 + 32 * i;
        const float* p = A32p + (size_t)(bm * 128 + row) * KDIM + c * 8;
        aF[i][0] = *(const float4*)p;
        aF[i][1] = *(const float4*)(p + 4);
        bR[i] = *(const int4*)(Wt + (size_t)(bn * 128 + row) * KDIM + c * 8);
    }

    floatx4 acc[4][4] = {};

    for (int kt = 0; kt < KDIM / 64; ++kt) {
        __syncthreads();
        #pragma unroll
        for (int i = 0; i < 4; ++i) {
            const int row = r0 + 32 * i;
            half8 h;
            h[0] = (_Float16)aF[i][0].x; h[1] = (_Float16)aF[i][0].y;
            h[2] = (_Float16)aF[i][0].z; h[3] = (_Float16)aF[i][0].w;
            h[4] = (_Float16)aF[i][1].x; h[5] = (_Float16)aF[i][1].y;
            h[6] = (_Float16)aF[i][1].z; h[7] = (_Float16)aF[i][1].w;
            *(half8*)&As[row * 64 + wcol] = h;
            *(int4*)&Bs[row * 64 + wcol] = bR[i];
        }
        __syncthreads();

        if (kt + 1 < KDIM / 64) {
            #pragma unroll
            for (int i = 0; i < 4; ++i) {
                const int row = r0 + 32 * i;
                const float* p = A32p + (size_t)(bm * 128 + row) * KDIM + (kt + 1) * 64 + c * 8;
                aF[i][0] = *(const float4*)p;
                aF[i][1] = *(const float4*)(p + 4);
                bR[i] = *(const int4*)(Wt + (size_t)(bn * 128 + row) * KDIM + (kt + 1) * 64 + c * 8);
            }
        }

        #pragma unroll
        for (int s = 0; s < 2; ++s) {
            half8 afr[4], bfr[4];
            const int colr = s * 32 + (lane >> 4) * 8;
            #pragma unroll
            for (int m = 0; m < 4; ++m) {
                const int row = wm * 64 + m * 16 + (lane & 15);
                afr[m] = *(const half8*)&As[row * 64 + (colr ^ ((row & 7) << 3))];
            }
            #pragma unroll
            for (int n = 0; n < 4; ++n) {
                const int row = wn * 64 + n * 16 + (lane & 15);
                bfr[n] = *(const half8*)&Bs[row * 64 + (colr ^ ((row & 7) << 3))];
            }
            #pragma unroll
            for (int m = 0; m < 4; ++m)
                #pragma unroll
                for (int n = 0; n < 4; ++n)
                    acc[m][n] = __builtin_amdgcn_mfma_f32_16x16x32_f16(
                        afr[m], bfr[n], acc[m][n], 0, 0, 0);
        }
    }

    float bv[4], cv[4];
    #pragma unroll
    for (int n = 0; n < 4; ++n) {
        const int col = bn * 128 + wn * 64 + n * 16 + (lane & 15);
        bv[n] = bias[col];
        cv[n] = ctx[col];
    }
    #pragma unroll
    for (int m = 0; m < 4; ++m) {
        #pragma unroll
        for (int j = 0; j < 4; ++j) {
            float partial = 0.0f;
            #pragma unroll
            for (int n = 0; n < 4; ++n) {
                const float v = acc[m][n][j] + bv[n];
                const float e = __expf(2.0f * v);
                const float t = 1.0f - 2.0f * __builtin_amdgcn_rcpf(e + 1.0f);
                partial += t * cv[n];
            }
            #pragma unroll
            for (int off = 1; off < 16; off <<= 1)
                partial += __shfl_xor(partial, off, 64);
            if ((lane & 15) == 0) {
                const int rowg = bm * 128 + wm * 64 + m * 16 + (lane >> 4) * 4 + j;
                atomicAdd(&scores[rowg], partial);
            }
        }
    }
}

// ---------------------------------------------------------------------------
// Kernel 4: softmax over seq dim per batch. 32 blocks x 256 threads.
// ---------------------------------------------------------------------------
__global__ void softmax_kernel(const float* __restrict__ scores,
                               float* __restrict__ weights) {
    const int bb = blockIdx.x;
    const int tid = threadIdx.x;
    const float* s = scores + (size_t)bb * SEQ;
    float* w = weights + (size_t)bb * SEQ;

    __shared__ float red[8];

    float v[8];
    float mx = -1e30f;
    #pragma unroll
    for (int i = 0; i < 8; ++i) {
        v[i] = s[tid + i * 256];
        mx = fmaxf(mx, v[i]);
    }
    #pragma unroll
    for (int off = 1; off < 64; off <<= 1)
        mx = fmaxf(mx, __shfl_xor(mx, off, 64));
    const int wv = tid >> 6;
    if ((tid & 63) == 0) red[wv] = mx;
    __syncthreads();
    mx = fmaxf(fmaxf(red[0], red[1]), fmaxf(red[2], red[3]));

    float sum = 0.0f;
    #pragma unroll
    for (int i = 0; i < 8; ++i) {
        v[i] = __expf(v[i] - mx);
        sum += v[i];
    }
    #pragma unroll
    for (int off = 1; off < 64; off <<= 1)
        sum += __shfl_xor(sum, off, 64);
    if ((tid & 63) == 0) red[4 + wv] = sum;
    __syncthreads();
    sum = red[4] + red[5] + red[6] + red[7];
    const float inv = 1.0f / sum;
    #pragma unroll
    for (int i = 0; i < 8; ++i)
        w[tid + i * 256] = v[i] * inv;
}

// ---------------------------------------------------------------------------
// Kernel 5: weighted pooling (fp32 fallback).
// ---------------------------------------------------------------------------
__global__ __launch_bounds__(256) void pool_kernel(const float* __restrict__ x,
                                                   const float* __restrict__ weights,
                                                   float* __restrict__ out) {
    const int bb = blockIdx.x >> 4;
    const int sc = blockIdx.x & 15;
    const int tid = threadIdx.x;

    const float4* xb = (const float4*)(x + (size_t)bb * SEQ * EMBED) +
                       (size_t)(sc * 128) * (EMBED / 4) + tid;
    const float* wb = weights + (size_t)bb * SEQ + sc * 128;

    float ax = 0.f, ay = 0.f, az = 0.f, aw = 0.f;
    #pragma unroll 4
    for (int s = 0; s < 128; ++s) {
        const float wgt = wb[s];
        const float4 xv = xb[(size_t)s * (EMBED / 4)];
        ax += wgt * xv.x; ay += wgt * xv.y; az += wgt * xv.z; aw += wgt * xv.w;
    }
    float* o = out + (size_t)bb * EMBED + tid * 4;
    atomicAdd(o + 0, ax);
    atomicAdd(o + 1, ay);
    atomicAdd(o + 2, az);
    atomicAdd(o + 3, aw);
}

// ---------------------------------------------------------------------------
// Kernel 5b: weighted pooling (fp16 x16) — halves the read bytes.
// ---------------------------------------------------------------------------
__global__ __launch_bounds__(256) void pool16_kernel(const _Float16* __restrict__ x16,
                                                     const float* __restrict__ weights,
                                                     float* __restrict__ out) {
    const int bb = blockIdx.x >> 4;
    const int sc = blockIdx.x & 15;
    const int tid = threadIdx.x;

    const _Float16* xb = x16 + (size_t)bb * SEQ * EMBED +
                         (size_t)(sc * 128) * EMBED + tid * 4;
    const float* wb = weights + (size_t)bb * SEQ + sc * 128;

    float ax = 0.f, ay = 0.f, az = 0.f, aw = 0.f;
    #pragma unroll 4
    for (int s = 0; s < 128; ++s) {
        const float wgt = wb[s];
        const half4 h = *(const half4*)(xb + (size_t)s * EMBED);
        ax += wgt * (float)h[0]; ay += wgt * (float)h[1];
        az += wgt * (float)h[2]; aw += wgt * (float)h[3];
    }
    float* o = out + (size_t)bb * EMBED + tid * 4;
    atomicAdd(o + 0, ax);
    atomicAdd(o + 1, ay);
    atomicAdd(o + 2, az);
    atomicAdd(o + 3, aw);
}

// ---------------------------------------------------------------------------
extern "C" void kernel_launch(void* const* d_in, const int* in_sizes, int n_in,
                              void* d_out, int out_size, void* d_ws, size_t ws_size,
                              hipStream_t stream) {
    const float* x   = (const float*)d_in[0];
    const float* W   = (const float*)d_in[1];
    const float* b   = (const float*)d_in[2];
    const float* ctx = (const float*)d_in[3];
    float* out = (float*)d_out;

    char* ws = (char*)d_ws;
    _Float16* Wt      = (_Float16*)ws;                               // 2 MB
    float*    scores  = (float*)(ws + (2u << 20));                   // 256 KB
    float*    weights = (float*)(ws + (2u << 20) + (256u << 10));    // 256 KB
    _Float16* x16     = (_Float16*)(ws + (4u << 20));                // 128 MB

    const size_t need = (4ull << 20) + ((size_t)M_TOT * KDIM * 2);
    const bool fast = ws_size >= need;

    hipLaunchKernelGGL(zero_kernel, dim3(M_TOT / 256), dim3(256), 0, stream, scores, out);
    hipLaunchKernelGGL(transpose_w_kernel, dim3(32, 32), dim3(32, 8), 0, stream, W, Wt);

    if (fast) {
        hipLaunchKernelGGL(cvt_x_kernel, dim3(4096), dim3(256), 0, stream, x, x16);
        hipLaunchKernelGGL(score_gemm14, dim3(2048), dim3(512), 0, stream,
                           x16, Wt, b, ctx, scores);
    } else {
        hipLaunchKernelGGL(score_gemm_f32, dim3(4096), dim3(256), 0, stream,
                           x, Wt, b, ctx, scores);
    }

    hipLaunchKernelGGL(softmax_kernel, dim3(BATCH), dim3(256), 0, stream, scores, weights);

    if (fast) {
        hipLaunchKernelGGL(pool16_kernel, dim3(BATCH * 16), dim3(256), 0, stream,
                           x16, weights, out);
    } else {
        hipLaunchKernelGGL(pool_kernel, dim3(BATCH * 16), dim3(256), 0, stream,
                           x, weights, out);
    }
}

// Round 21
// 283.936 us; speedup vs baseline: 1.9405x; 1.0116x over previous
//
#include <hip/hip_runtime.h>
#include <hip/hip_bf16.h>

typedef _Float16 half8 __attribute__((ext_vector_type(8)));
typedef _Float16 half4 __attribute__((ext_vector_type(4)));
typedef float floatx4 __attribute__((ext_vector_type(4)));

#define EMBED 1024
#define SEQ   2048
#define BATCH 32
#define M_TOT (BATCH * SEQ)   // 65536 rows
#define KDIM  1024
#define NDIM  1024

// async global->LDS, 16B per lane, dest = wave-uniform base + lane*16
#define GLOAD16(g, l) __builtin_amdgcn_global_load_lds(                      \
    (const __attribute__((address_space(1))) void*)(g),                      \
    (__attribute__((address_space(3))) void*)(l), 16, 0, 0)

// ---------------------------------------------------------------------------
// Kernel 1: transpose + convert W[K][N] fp32 -> Wt[N][K] fp16
// ---------------------------------------------------------------------------
__global__ void transpose_w_kernel(const float* __restrict__ W,
                                   _Float16* __restrict__ Wt) {
    __shared__ float t[32][33];
    const int kt = blockIdx.x * 32;
    const int nt = blockIdx.y * 32;
    #pragma unroll
    for (int i = 0; i < 4; ++i)
        t[threadIdx.y + 8 * i][threadIdx.x] =
            W[(size_t)(kt + threadIdx.y + 8 * i) * NDIM + nt + threadIdx.x];
    __syncthreads();
    #pragma unroll
    for (int i = 0; i < 4; ++i)
        Wt[(size_t)(nt + threadIdx.y + 8 * i) * KDIM + kt + threadIdx.x] =
            (_Float16)t[threadIdx.x][threadIdx.y + 8 * i];
}

// ---------------------------------------------------------------------------
// Kernel 2: zero scores + out
// ---------------------------------------------------------------------------
__global__ void zero_kernel(float* __restrict__ scores, float* __restrict__ out) {
    const int i = blockIdx.x * 256 + threadIdx.x;
    if (i < M_TOT) scores[i] = 0.0f;
    if (i < BATCH * EMBED) out[i] = 0.0f;
}

// ---------------------------------------------------------------------------
// Kernel 3: fused scores GEMM — r10 structure, A STAGED AS FP32 (no cvt_x
// pass; r13 redone with the spill + swizzle fixed).
// BM=128, BN=128, BK=32, 256 threads (2x2 waves, 64x64 wave-tile),
// mfma_f32_16x16x32_f16, counted vmcnt (r14-proven loop).
//   A (fp32): [128 rows][32 floats] = 128B rows, 8 x 16B slots.  Swizzle
//     key row&7: stage lane l -> row j*8+(l>>3), LDS slot l&7 linear,
//     GLOBAL slot g = (l&7) ^ ((l>>3)&7); read frag slots s = 2*fhi+c,
//     phys p = s ^ (frow&7).  Bank-verified: any 8-lane issue group covers
//     8 distinct slots = all 32 banks.
//   B (fp16): byte-identical to r16 (64B rows, key (row>>1)&3, 0 conflicts).
// fp32->fp16 convert per-m at frag read (VALU 24% busy has headroom).
// LDS 48 KB -> 3 blocks/CU; launch_bounds(256,3) = 170 regs/thread so the
// fp32 temporaries do NOT spill (r13's 628 MB WRITE failure mode).
// Staging: A 16 instr (4/wave), B 8 instr (2/wave) => 6 loads/wave/tile,
// steady-state s_waitcnt vmcnt(6).
// ---------------------------------------------------------------------------
__global__ __launch_bounds__(256, 3) void score_gemm17(
    const float* __restrict__ x, const _Float16* __restrict__ Wt,
    const float* __restrict__ bias, const float* __restrict__ ctx,
    float* __restrict__ scores) {
    __shared__ float    Asf[2][128 * 32];  // 16 KB per buf
    __shared__ _Float16 Bs[2][128 * 32];   // 8 KB per buf   (total 48 KB)

    // XCD-aware chunk swizzle (4096 blocks, 8 XCDs, bijective)
    const int nb = ((blockIdx.x & 7) << 9) | (blockIdx.x >> 3);
    const int bm = nb >> 3;       // 512 row tiles, contiguous per XCD
    const int bn = nb & 7;        // 8 col tiles, innermost per XCD
    const int tid = threadIdx.x;
    const int lane = tid & 63;
    const int wid = tid >> 6;     // 0..3
    const int wm = wid >> 1;
    const int wn = wid & 1;

    // ---- A staging (fp32, 128B rows): instr j covers rows j*8..j*8+7;
    //      wave w owns j in {4w..4w+3}.  lane l -> row j*8+(l>>3), slot l&7.
    const int arow = lane >> 3;                       // 0..7
    const int agsl = (lane & 7) ^ arow;               // pre-swizzled global slot
    // ---- B staging (fp16, 64B rows): instr j covers rows j*16..j*16+15;
    //      wave w owns {w, w+4}.  lane l -> row j*16+(l>>2), slot l&3.
    const int brow = lane >> 2;                       // 0..15
    const int bgsl = (lane & 3) ^ ((lane >> 3) & 3);  // key (row>>1)&3

    const float*    Ab = x  + (size_t)(bm * 128) * KDIM;
    const _Float16* Bb = Wt + (size_t)(bn * 128) * KDIM;

    floatx4 acc[4][4] = {};

    // frag read geometry
    const int frow = lane & 15;
    const int fhi  = lane >> 4;        // 0..3
    const int afx  = frow & 7;         // A read XOR key
    const int bslot = ((fhi) ^ ((frow >> 1) & 3)) * 8;   // B phys (halves)

    #define STAGE(buf, kt)                                                        \
        {                                                                         \
            _Pragma("unroll")                                                     \
            for (int i = 0; i < 4; ++i) {                                         \
                const int j = wid * 4 + i;                                        \
                GLOAD16(Ab + (size_t)(j * 8 + arow) * KDIM + (kt) * 32 + agsl * 4, \
                        &Asf[buf][(j * 8) * 32]);                                 \
            }                                                                     \
            _Pragma("unroll")                                                     \
            for (int i = 0; i < 2; ++i) {                                         \
                const int j = wid + i * 4;                                        \
                GLOAD16(Bb + (size_t)(j * 16 + brow) * KDIM + (kt) * 32 + bgsl * 8, \
                        &Bs[buf][j * 512]);                                       \
            }                                                                     \
        }

    #define COMPUTE(buf)                                                          \
        {                                                                         \
            half8 bfr[4];                                                         \
            _Pragma("unroll")                                                     \
            for (int n = 0; n < 4; ++n)                                           \
                bfr[n] = *(const half8*)&Bs[buf][(wn * 64 + n * 16 + frow) * 32 + bslot]; \
            _Pragma("unroll")                                                     \
            for (int m = 0; m < 4; ++m) {                                         \
                const int r = wm * 64 + m * 16 + frow;                            \
                const floatx4 f0 = *(const floatx4*)&Asf[buf][r * 32 +            \
                                        (((2 * fhi) ^ afx) * 4)];                 \
                const floatx4 f1 = *(const floatx4*)&Asf[buf][r * 32 +            \
                                        (((2 * fhi + 1) ^ afx) * 4)];             \
                half8 a;                                                          \
                a[0] = (_Float16)f0[0]; a[1] = (_Float16)f0[1];                   \
                a[2] = (_Float16)f0[2]; a[3] = (_Float16)f0[3];                   \
                a[4] = (_Float16)f1[0]; a[5] = (_Float16)f1[1];                   \
                a[6] = (_Float16)f1[2]; a[7] = (_Float16)f1[3];                   \
                _Pragma("unroll")                                                 \
                for (int n = 0; n < 4; ++n)                                       \
                    acc[m][n] = __builtin_amdgcn_mfma_f32_16x16x32_f16(           \
                        a, bfr[n], acc[m][n], 0, 0, 0);                           \
            }                                                                     \
        }

    STAGE(0, 0);               // 6 loads/wave in flight (tile 0)

    for (int kt = 0; kt < 31; ++kt) {
        const int cur = kt & 1;
        STAGE(cur ^ 1, kt + 1);                 // +6 -> 12 in flight
        asm volatile("s_waitcnt vmcnt(6)" ::: "memory");  // tile kt done; kt+1 stays
        __builtin_amdgcn_sched_barrier(0);
        __builtin_amdgcn_s_barrier();           // block-wide: tile kt ready
        COMPUTE(cur);
        __builtin_amdgcn_s_barrier();           // reads done; buf reusable
    }
    // kt = 31 (cur = 1): drain the last 6
    asm volatile("s_waitcnt vmcnt(0)" ::: "memory");
    __builtin_amdgcn_sched_barrier(0);
    __builtin_amdgcn_s_barrier();
    COMPUTE(1);

    #undef COMPUTE
    #undef STAGE

    // ---- epilogue: fast tanh + ctx dot + 16-lane reduce + atomic ----
    float bv[4], cv[4];
    #pragma unroll
    for (int n = 0; n < 4; ++n) {
        const int col = bn * 128 + wn * 64 + n * 16 + frow;
        bv[n] = bias[col];
        cv[n] = ctx[col];
    }
    #pragma unroll
    for (int m = 0; m < 4; ++m) {
        #pragma unroll
        for (int j = 0; j < 4; ++j) {
            float partial = 0.0f;
            #pragma unroll
            for (int n = 0; n < 4; ++n) {
                const float v = acc[m][n][j] + bv[n];
                const float e = __expf(2.0f * v);          // tanh(v)=1-2/(e^{2v}+1)
                const float t = 1.0f - 2.0f * __builtin_amdgcn_rcpf(e + 1.0f);
                partial += t * cv[n];
            }
            #pragma unroll
            for (int off = 1; off < 16; off <<= 1)
                partial += __shfl_xor(partial, off, 64);
            if (frow == 0) {
                const int rowg = bm * 128 + wm * 64 + m * 16 + fhi * 4 + j;
                atomicAdd(&scores[rowg], partial);
            }
        }
    }
}

// ---------------------------------------------------------------------------
// Fallback GEMM (ws too small): reg-staged fp32 path.
// ---------------------------------------------------------------------------
__global__ __launch_bounds__(256) void score_gemm_f32(
    const float* __restrict__ A32p, const _Float16* __restrict__ Wt,
    const float* __restrict__ bias, const float* __restrict__ ctx,
    float* __restrict__ scores) {
    __shared__ _Float16 As[128 * 64];
    __shared__ _Float16 Bs[128 * 64];

    const int bid = blockIdx.x;
    const int bm = bid >> 3;
    const int bn = bid & 7;
    const int tid = threadIdx.x;
    const int lane = tid & 63;
    const int wid = tid >> 6;
    const int wm = wid >> 1;
    const int wn = wid & 1;

    const int c = tid & 7;
    const int r0 = tid >> 3;
    const int swz = (r0 & 7) << 3;
    const int wcol = (c * 8) ^ swz;

    float4 aF[4][2];
    int4   bR[4];

    #pragma unroll
    for (int i = 0; i < 4; ++i) {
        const int row = r0 + 32 * i;
        const float* p = A32p + (size_t)(bm * 128 + row) * KDIM + c * 8;
        aF[i][0] = *(const float4*)p;
        aF[i][1] = *(const float4*)(p + 4);
        bR[i] = *(const int4*)(Wt + (size_t)(bn * 128 + row) * KDIM + c * 8);
    }

    floatx4 acc[4][4] = {};

    for (int kt = 0; kt < KDIM / 64; ++kt) {
        __syncthreads();
        #pragma unroll
        for (int i = 0; i < 4; ++i) {
            const int row = r0 + 32 * i;
            half8 h;
            h[0] = (_Float16)aF[i][0].x; h[1] = (_Float16)aF[i][0].y;
            h[2] = (_Float16)aF[i][0].z; h[3] = (_Float16)aF[i][0].w;
            h[4] = (_Float16)aF[i][1].x; h[5] = (_Float16)aF[i][1].y;
            h[6] = (_Float16)aF[i][1].z; h[7] = (_Float16)aF[i][1].w;
            *(half8*)&As[row * 64 + wcol] = h;
            *(int4*)&Bs[row * 64 + wcol] = bR[i];
        }
        __syncthreads();

        if (kt + 1 < KDIM / 64) {
            #pragma unroll
            for (int i = 0; i < 4; ++i) {
                const int row = r0 + 32 * i;
                const float* p = A32p + (size_t)(bm * 128 + row) * KDIM + (kt + 1) * 64 + c * 8;
                aF[i][0] = *(const float4*)p;
                aF[i][1] = *(const float4*)(p + 4);
                bR[i] = *(const int4*)(Wt + (size_t)(bn * 128 + row) * KDIM + (kt + 1) * 64 + c * 8);
            }
        }

        #pragma unroll
        for (int s = 0; s < 2; ++s) {
            half8 afr[4], bfr[4];
            const int colr = s * 32 + (lane >> 4) * 8;
            #pragma unroll
            for (int m = 0; m < 4; ++m) {
                const int row = wm * 64 + m * 16 + (lane & 15);
                afr[m] = *(const half8*)&As[row * 64 + (colr ^ ((row & 7) << 3))];
            }
            #pragma unroll
            for (int n = 0; n < 4; ++n) {
                const int row = wn * 64 + n * 16 + (lane & 15);
                bfr[n] = *(const half8*)&Bs[row * 64 + (colr ^ ((row & 7) << 3))];
            }
            #pragma unroll
            for (int m = 0; m < 4; ++m)
                #pragma unroll
                for (int n = 0; n < 4; ++n)
                    acc[m][n] = __builtin_amdgcn_mfma_f32_16x16x32_f16(
                        afr[m], bfr[n], acc[m][n], 0, 0, 0);
        }
    }

    float bv[4], cv[4];
    #pragma unroll
    for (int n = 0; n < 4; ++n) {
        const int col = bn * 128 + wn * 64 + n * 16 + (lane & 15);
        bv[n] = bias[col];
        cv[n] = ctx[col];
    }
    #pragma unroll
    for (int m = 0; m < 4; ++m) {
        #pragma unroll
        for (int j = 0; j < 4; ++j) {
            float partial = 0.0f;
            #pragma unroll
            for (int n = 0; n < 4; ++n) {
                const float v = acc[m][n][j] + bv[n];
                const float e = __expf(2.0f * v);
                const float t = 1.0f - 2.0f * __builtin_amdgcn_rcpf(e + 1.0f);
                partial += t * cv[n];
            }
            #pragma unroll
            for (int off = 1; off < 16; off <<= 1)
                partial += __shfl_xor(partial, off, 64);
            if ((lane & 15) == 0) {
                const int rowg = bm * 128 + wm * 64 + m * 16 + (lane >> 4) * 4 + j;
                atomicAdd(&scores[rowg], partial);
            }
        }
    }
}

// ---------------------------------------------------------------------------
// Kernel 4: softmax over seq dim per batch. 32 blocks x 256 threads.
// ---------------------------------------------------------------------------
__global__ void softmax_kernel(const float* __restrict__ scores,
                               float* __restrict__ weights) {
    const int bb = blockIdx.x;
    const int tid = threadIdx.x;
    const float* s = scores + (size_t)bb * SEQ;
    float* w = weights + (size_t)bb * SEQ;

    __shared__ float red[8];

    float v[8];
    float mx = -1e30f;
    #pragma unroll
    for (int i = 0; i < 8; ++i) {
        v[i] = s[tid + i * 256];
        mx = fmaxf(mx, v[i]);
    }
    #pragma unroll
    for (int off = 1; off < 64; off <<= 1)
        mx = fmaxf(mx, __shfl_xor(mx, off, 64));
    const int wv = tid >> 6;
    if ((tid & 63) == 0) red[wv] = mx;
    __syncthreads();
    mx = fmaxf(fmaxf(red[0], red[1]), fmaxf(red[2], red[3]));

    float sum = 0.0f;
    #pragma unroll
    for (int i = 0; i < 8; ++i) {
        v[i] = __expf(v[i] - mx);
        sum += v[i];
    }
    #pragma unroll
    for (int off = 1; off < 64; off <<= 1)
        sum += __shfl_xor(sum, off, 64);
    if ((tid & 63) == 0) red[4 + wv] = sum;
    __syncthreads();
    sum = red[4] + red[5] + red[6] + red[7];
    const float inv = 1.0f / sum;
    #pragma unroll
    for (int i = 0; i < 8; ++i)
        w[tid + i * 256] = v[i] * inv;
}

// ---------------------------------------------------------------------------
// Kernel 5: weighted pooling (fp32 x).  out[b,e] = sum_s w[b,s] * x[b,s,e]
// ---------------------------------------------------------------------------
__global__ __launch_bounds__(256) void pool_kernel(const float* __restrict__ x,
                                                   const float* __restrict__ weights,
                                                   float* __restrict__ out) {
    const int bb = blockIdx.x >> 4;
    const int sc = blockIdx.x & 15;
    const int tid = threadIdx.x;

    const float4* xb = (const float4*)(x + (size_t)bb * SEQ * EMBED) +
                       (size_t)(sc * 128) * (EMBED / 4) + tid;
    const float* wb = weights + (size_t)bb * SEQ + sc * 128;

    float ax = 0.f, ay = 0.f, az = 0.f, aw = 0.f;
    #pragma unroll 4
    for (int s = 0; s < 128; ++s) {
        const float wgt = wb[s];
        const float4 xv = xb[(size_t)s * (EMBED / 4)];
        ax += wgt * xv.x; ay += wgt * xv.y; az += wgt * xv.z; aw += wgt * xv.w;
    }
    float* o = out + (size_t)bb * EMBED + tid * 4;
    atomicAdd(o + 0, ax);
    atomicAdd(o + 1, ay);
    atomicAdd(o + 2, az);
    atomicAdd(o + 3, aw);
}

// ---------------------------------------------------------------------------
extern "C" void kernel_launch(void* const* d_in, const int* in_sizes, int n_in,
                              void* d_out, int out_size, void* d_ws, size_t ws_size,
                              hipStream_t stream) {
    const float* x   = (const float*)d_in[0];
    const float* W   = (const float*)d_in[1];
    const float* b   = (const float*)d_in[2];
    const float* ctx = (const float*)d_in[3];
    float* out = (float*)d_out;

    char* ws = (char*)d_ws;
    _Float16* Wt      = (_Float16*)ws;                               // 2 MB
    float*    scores  = (float*)(ws + (2u << 20));                   // 256 KB
    float*    weights = (float*)(ws + (2u << 20) + (256u << 10));    // 256 KB

    const bool fast = ws_size >= (4ull << 20);

    hipLaunchKernelGGL(zero_kernel, dim3(M_TOT / 256), dim3(256), 0, stream, scores, out);
    hipLaunchKernelGGL(transpose_w_kernel, dim3(32, 32), dim3(32, 8), 0, stream, W, Wt);

    if (fast) {
        hipLaunchKernelGGL(score_gemm17, dim3(4096), dim3(256), 0, stream,
                           x, Wt, b, ctx, scores);
    } else {
        hipLaunchKernelGGL(score_gemm_f32, dim3(4096), dim3(256), 0, stream,
                           x, Wt, b, ctx, scores);
    }

    hipLaunchKernelGGL(softmax_kernel, dim3(BATCH), dim3(256), 0, stream, scores, weights);
    hipLaunchKernelGGL(pool_kernel, dim3(BATCH * 16), dim3(256), 0, stream,
                       x, weights, out);
}